// Round 4
// baseline (95.263 us; speedup 1.0000x reference)
//
#include <hip/hip_runtime.h>

#define EPS 1e-5f
#define THREADS 256
#define MAIN_BLOCKS 2048
#define SUPER 2048               // float4 elements per main block-iteration (32 KB/array)

// ---------------------------------------------------------------------------
// Single fused kernel.
//   blocks [0, nBnd)            : boundary gather (subtract first/last of each
//                                 segment) -> negative partial
//   blocks [nBnd, nBnd+MAIN_BLOCKS): streaming sum of nll over superchunks
// Each block stores its partial to ws[blockIdx.x] (agent-scope atomic store),
// then bumps a device-scope counter; the LAST block to finish reduces all
// partials and writes out[0] = sum * inv_div.
// Counter (ws[npart]) is zeroed by a 4-byte hipMemsetAsync before launch.
// ---------------------------------------------------------------------------
__global__ __launch_bounds__(THREADS, 4) void tau_loss_fused(
    const float4* __restrict__ t4,
    const float4* __restrict__ d4,
    const float* __restrict__ tau,
    const float* __restrict__ dt,
    const int* __restrict__ offsets,
    float* __restrict__ ws,
    int* __restrict__ counter,
    int n, int nseg, int nBnd, float inv_div,
    float* __restrict__ out) {

    float partial = 0.0f;

    if ((int)blockIdx.x < nBnd) {
        // ---------------- boundary role ----------------
        int k = blockIdx.x * THREADS + threadIdx.x;
        float sub = 0.0f;
        if (k < nseg) {
            int s = offsets[k];
            int e = offsets[k + 1] - 1;
            float ts = tau[s];
            sub = __logf(ts) + __fdividef(dt[s] + EPS, ts);
            if (e != s) {
                float te = tau[e];
                sub += __logf(te) + __fdividef(dt[e] + EPS, te);
            }
        }
        partial = -sub;
    } else {
        // ---------------- main streaming role ----------------
        const int mb = (int)blockIdx.x - nBnd;
        const int n4 = n >> 2;
        const int nsuper = n4 / SUPER;

        float a0 = 0.f, a1 = 0.f, a2 = 0.f, a3 = 0.f;

        for (int s = mb; s < nsuper; s += MAIN_BLOCKS) {
            const int base = s * SUPER + (int)threadIdx.x;
            // ---- issue all 16 loads back-to-back, no intervening use ----
            float4 t0 = t4[base + 0 * THREADS];
            float4 t1 = t4[base + 1 * THREADS];
            float4 t2 = t4[base + 2 * THREADS];
            float4 t3 = t4[base + 3 * THREADS];
            float4 t4v = t4[base + 4 * THREADS];
            float4 t5 = t4[base + 5 * THREADS];
            float4 t6 = t4[base + 6 * THREADS];
            float4 t7 = t4[base + 7 * THREADS];
            float4 e0 = d4[base + 0 * THREADS];
            float4 e1 = d4[base + 1 * THREADS];
            float4 e2 = d4[base + 2 * THREADS];
            float4 e3 = d4[base + 3 * THREADS];
            float4 e4 = d4[base + 4 * THREADS];
            float4 e5 = d4[base + 5 * THREADS];
            float4 e6 = d4[base + 6 * THREADS];
            float4 e7 = d4[base + 7 * THREADS];
            // ---- compute ----
            a0 += __logf(t0.x) + __fdividef(e0.x + EPS, t0.x);
            a1 += __logf(t0.y) + __fdividef(e0.y + EPS, t0.y);
            a2 += __logf(t0.z) + __fdividef(e0.z + EPS, t0.z);
            a3 += __logf(t0.w) + __fdividef(e0.w + EPS, t0.w);
            a0 += __logf(t1.x) + __fdividef(e1.x + EPS, t1.x);
            a1 += __logf(t1.y) + __fdividef(e1.y + EPS, t1.y);
            a2 += __logf(t1.z) + __fdividef(e1.z + EPS, t1.z);
            a3 += __logf(t1.w) + __fdividef(e1.w + EPS, t1.w);
            a0 += __logf(t2.x) + __fdividef(e2.x + EPS, t2.x);
            a1 += __logf(t2.y) + __fdividef(e2.y + EPS, t2.y);
            a2 += __logf(t2.z) + __fdividef(e2.z + EPS, t2.z);
            a3 += __logf(t2.w) + __fdividef(e2.w + EPS, t2.w);
            a0 += __logf(t3.x) + __fdividef(e3.x + EPS, t3.x);
            a1 += __logf(t3.y) + __fdividef(e3.y + EPS, t3.y);
            a2 += __logf(t3.z) + __fdividef(e3.z + EPS, t3.z);
            a3 += __logf(t3.w) + __fdividef(e3.w + EPS, t3.w);
            a0 += __logf(t4v.x) + __fdividef(e4.x + EPS, t4v.x);
            a1 += __logf(t4v.y) + __fdividef(e4.y + EPS, t4v.y);
            a2 += __logf(t4v.z) + __fdividef(e4.z + EPS, t4v.z);
            a3 += __logf(t4v.w) + __fdividef(e4.w + EPS, t4v.w);
            a0 += __logf(t5.x) + __fdividef(e5.x + EPS, t5.x);
            a1 += __logf(t5.y) + __fdividef(e5.y + EPS, t5.y);
            a2 += __logf(t5.z) + __fdividef(e5.z + EPS, t5.z);
            a3 += __logf(t5.w) + __fdividef(e5.w + EPS, t5.w);
            a0 += __logf(t6.x) + __fdividef(e6.x + EPS, t6.x);
            a1 += __logf(t6.y) + __fdividef(e6.y + EPS, t6.y);
            a2 += __logf(t6.z) + __fdividef(e6.z + EPS, t6.z);
            a3 += __logf(t6.w) + __fdividef(e6.w + EPS, t6.w);
            a0 += __logf(t7.x) + __fdividef(e7.x + EPS, t7.x);
            a1 += __logf(t7.y) + __fdividef(e7.y + EPS, t7.y);
            a2 += __logf(t7.z) + __fdividef(e7.z + EPS, t7.z);
            a3 += __logf(t7.w) + __fdividef(e7.w + EPS, t7.w);
        }

        // scalar tail (none for N=16.7M; kept general)
        if (mb == 0) {
            for (int i = nsuper * (SUPER * 4) + (int)threadIdx.x; i < n; i += THREADS) {
                float t = tau[i];
                a0 += __logf(t) + __fdividef(dt[i] + EPS, t);
            }
        }
        partial = (a0 + a1) + (a2 + a3);
    }

    // ---- block reduce partial ----
    #pragma unroll
    for (int off = 32; off > 0; off >>= 1)
        partial += __shfl_down(partial, off, 64);

    __shared__ float smem[THREADS / 64];
    __shared__ int flag;
    int wave = threadIdx.x >> 6;
    int lane = threadIdx.x & 63;
    if (lane == 0) smem[wave] = partial;
    __syncthreads();

    if (threadIdx.x == 0) {
        float p = smem[0] + smem[1] + smem[2] + smem[3];
        // agent-scope (device) atomic store: coherent across XCD L2s
        __hip_atomic_store(&ws[blockIdx.x], p, __ATOMIC_RELAXED,
                           __HIP_MEMORY_SCOPE_AGENT);
        int old = __hip_atomic_fetch_add(counter, 1, __ATOMIC_ACQ_REL,
                                         __HIP_MEMORY_SCOPE_AGENT);
        flag = (old == (int)gridDim.x - 1) ? 1 : 0;
    }
    __syncthreads();

    if (flag) {
        // ---- last block standing: reduce all partials ----
        const int total = (int)gridDim.x;
        float b0 = 0.f, b1 = 0.f, b2 = 0.f, b3 = 0.f;
        int i = (int)threadIdx.x;
        for (; i + 3 * THREADS < total; i += 4 * THREADS) {
            b0 += __hip_atomic_load(&ws[i + 0 * THREADS], __ATOMIC_RELAXED,
                                    __HIP_MEMORY_SCOPE_AGENT);
            b1 += __hip_atomic_load(&ws[i + 1 * THREADS], __ATOMIC_RELAXED,
                                    __HIP_MEMORY_SCOPE_AGENT);
            b2 += __hip_atomic_load(&ws[i + 2 * THREADS], __ATOMIC_RELAXED,
                                    __HIP_MEMORY_SCOPE_AGENT);
            b3 += __hip_atomic_load(&ws[i + 3 * THREADS], __ATOMIC_RELAXED,
                                    __HIP_MEMORY_SCOPE_AGENT);
        }
        for (; i < total; i += THREADS)
            b0 += __hip_atomic_load(&ws[i], __ATOMIC_RELAXED,
                                    __HIP_MEMORY_SCOPE_AGENT);
        float a = (b0 + b1) + (b2 + b3);

        #pragma unroll
        for (int off = 32; off > 0; off >>= 1)
            a += __shfl_down(a, off, 64);

        __shared__ float smem2[THREADS / 64];
        if (lane == 0) smem2[wave] = a;
        __syncthreads();
        if (threadIdx.x == 0)
            out[0] = (smem2[0] + smem2[1] + smem2[2] + smem2[3]) * inv_div;
    }
}

extern "C" void kernel_launch(void* const* d_in, const int* in_sizes, int n_in,
                              void* d_out, int out_size, void* d_ws, size_t ws_size,
                              hipStream_t stream) {
    const float* tau = (const float*)d_in[0];
    const float* dt  = (const float*)d_in[1];
    const int* offsets = (const int*)d_in[2];
    float* out = (float*)d_out;
    float* ws = (float*)d_ws;

    const int n = in_sizes[0];
    const int n_off = in_sizes[2];          // B + 1
    const int nseg = n_off - 1;
    const float inv_div = 1.0f / (float)n_off;

    int nBnd = (nseg + THREADS - 1) / THREADS;   // boundary blocks (run first)
    if (nBnd < 1) nBnd = 1;
    const int grid = nBnd + MAIN_BLOCKS;
    int* counter = (int*)(ws + grid);

    // zero ONLY the finish-counter (4 bytes) each call — graph-capture safe
    hipMemsetAsync(counter, 0, sizeof(int), stream);

    tau_loss_fused<<<grid, THREADS, 0, stream>>>(
        (const float4*)tau, (const float4*)dt, tau, dt, offsets,
        ws, counter, n, nseg, nBnd, inv_div, out);
}

// Round 5
// 34.217 us; speedup vs baseline: 2.7841x; 2.7841x over previous
//
#include <hip/hip_runtime.h>

#define EPS 1e-5f
#define THREADS 256
#define MAIN_BLOCKS 2048
#define SUPER 2048               // float4 elements per block-iteration (32 KB/array)
#define BND_THREADS 256

// ---------------------------------------------------------------------------
// Kernel 1: full unmasked sum of nll = log(tau) + (dt+eps)/tau over all N.
// One 2048-float4 superchunk per block (exact cover at N=16.7M).
// 16 independent dwordx4 loads issued pairwise (t,e interleaved) before use:
// compute on chunk i needs only loads 2i,2i+1 -> compiler emits partial
// vmcnt waits and keeps the rest in flight. __launch_bounds__(256,2) gives
// the allocator a 256-VGPR cap so all 16 results can be simultaneously live
// (R3 lesson: (256,4) -> 48 VGPR -> half the batch serialized).
// ---------------------------------------------------------------------------
__global__ __launch_bounds__(THREADS, 2) void tau_loss_main(
    const float4* __restrict__ t4,
    const float4* __restrict__ d4,
    const float* __restrict__ tau,
    const float* __restrict__ dt,
    float* __restrict__ ws,
    int n) {
    const int n4 = n >> 2;
    const int nsuper = n4 / SUPER;

    float a0 = 0.f, a1 = 0.f, a2 = 0.f, a3 = 0.f;

    for (int s = blockIdx.x; s < nsuper; s += MAIN_BLOCKS) {
        const int base = s * SUPER + (int)threadIdx.x;
        // ---- issue all 16 loads back-to-back, pairwise t/e ----
        float4 t0 = t4[base + 0 * THREADS];
        float4 e0 = d4[base + 0 * THREADS];
        float4 t1 = t4[base + 1 * THREADS];
        float4 e1 = d4[base + 1 * THREADS];
        float4 t2 = t4[base + 2 * THREADS];
        float4 e2 = d4[base + 2 * THREADS];
        float4 t3 = t4[base + 3 * THREADS];
        float4 e3 = d4[base + 3 * THREADS];
        float4 t4v = t4[base + 4 * THREADS];
        float4 e4 = d4[base + 4 * THREADS];
        float4 t5 = t4[base + 5 * THREADS];
        float4 e5 = d4[base + 5 * THREADS];
        float4 t6 = t4[base + 6 * THREADS];
        float4 e6 = d4[base + 6 * THREADS];
        float4 t7 = t4[base + 7 * THREADS];
        float4 e7 = d4[base + 7 * THREADS];
        // ---- compute (chunk i depends only on loads 2i, 2i+1) ----
        a0 += __logf(t0.x) + __fdividef(e0.x + EPS, t0.x);
        a1 += __logf(t0.y) + __fdividef(e0.y + EPS, t0.y);
        a2 += __logf(t0.z) + __fdividef(e0.z + EPS, t0.z);
        a3 += __logf(t0.w) + __fdividef(e0.w + EPS, t0.w);
        a0 += __logf(t1.x) + __fdividef(e1.x + EPS, t1.x);
        a1 += __logf(t1.y) + __fdividef(e1.y + EPS, t1.y);
        a2 += __logf(t1.z) + __fdividef(e1.z + EPS, t1.z);
        a3 += __logf(t1.w) + __fdividef(e1.w + EPS, t1.w);
        a0 += __logf(t2.x) + __fdividef(e2.x + EPS, t2.x);
        a1 += __logf(t2.y) + __fdividef(e2.y + EPS, t2.y);
        a2 += __logf(t2.z) + __fdividef(e2.z + EPS, t2.z);
        a3 += __logf(t2.w) + __fdividef(e2.w + EPS, t2.w);
        a0 += __logf(t3.x) + __fdividef(e3.x + EPS, t3.x);
        a1 += __logf(t3.y) + __fdividef(e3.y + EPS, t3.y);
        a2 += __logf(t3.z) + __fdividef(e3.z + EPS, t3.z);
        a3 += __logf(t3.w) + __fdividef(e3.w + EPS, t3.w);
        a0 += __logf(t4v.x) + __fdividef(e4.x + EPS, t4v.x);
        a1 += __logf(t4v.y) + __fdividef(e4.y + EPS, t4v.y);
        a2 += __logf(t4v.z) + __fdividef(e4.z + EPS, t4v.z);
        a3 += __logf(t4v.w) + __fdividef(e4.w + EPS, t4v.w);
        a0 += __logf(t5.x) + __fdividef(e5.x + EPS, t5.x);
        a1 += __logf(t5.y) + __fdividef(e5.y + EPS, t5.y);
        a2 += __logf(t5.z) + __fdividef(e5.z + EPS, t5.z);
        a3 += __logf(t5.w) + __fdividef(e5.w + EPS, t5.w);
        a0 += __logf(t6.x) + __fdividef(e6.x + EPS, t6.x);
        a1 += __logf(t6.y) + __fdividef(e6.y + EPS, t6.y);
        a2 += __logf(t6.z) + __fdividef(e6.z + EPS, t6.z);
        a3 += __logf(t6.w) + __fdividef(e6.w + EPS, t6.w);
        a0 += __logf(t7.x) + __fdividef(e7.x + EPS, t7.x);
        a1 += __logf(t7.y) + __fdividef(e7.y + EPS, t7.y);
        a2 += __logf(t7.z) + __fdividef(e7.z + EPS, t7.z);
        a3 += __logf(t7.w) + __fdividef(e7.w + EPS, t7.w);
    }

    // scalar tail: elements past nsuper*SUPER*4 (none for N=16.7M; kept general)
    if (blockIdx.x == 0) {
        for (int i = nsuper * (SUPER * 4) + (int)threadIdx.x; i < n; i += THREADS) {
            float t = tau[i];
            a0 += __logf(t) + __fdividef(dt[i] + EPS, t);
        }
    }

    float acc = (a0 + a1) + (a2 + a3);

    #pragma unroll
    for (int off = 32; off > 0; off >>= 1)
        acc += __shfl_down(acc, off, 64);

    __shared__ float smem[THREADS / 64];
    int wave = threadIdx.x >> 6;
    int lane = threadIdx.x & 63;
    if (lane == 0) smem[wave] = acc;
    __syncthreads();
    if (threadIdx.x == 0)
        ws[blockIdx.x] = smem[0] + smem[1] + smem[2] + smem[3];
}

// ---------------------------------------------------------------------------
// Kernel 2: boundary (first & last of each segment) contributions, negated,
// stored to ws[MAIN_BLOCKS + blockIdx.x].
// ---------------------------------------------------------------------------
__global__ __launch_bounds__(BND_THREADS) void tau_loss_boundary(
    const float* __restrict__ tau,
    const float* __restrict__ dt,
    const int* __restrict__ offsets,
    float* __restrict__ ws,
    int nseg) {
    int k = blockIdx.x * blockDim.x + threadIdx.x;

    float sub = 0.0f;
    if (k < nseg) {
        int s = offsets[k];
        int e = offsets[k + 1] - 1;
        float ts = tau[s];
        sub = __logf(ts) + __fdividef(dt[s] + EPS, ts);
        if (e != s) {
            float te = tau[e];
            sub += __logf(te) + __fdividef(dt[e] + EPS, te);
        }
    }

    #pragma unroll
    for (int off = 32; off > 0; off >>= 1)
        sub += __shfl_down(sub, off, 64);

    __shared__ float smem[BND_THREADS / 64];
    int wave = threadIdx.x >> 6;
    int lane = threadIdx.x & 63;
    if (lane == 0) smem[wave] = sub;
    __syncthreads();
    if (threadIdx.x == 0)
        ws[MAIN_BLOCKS + blockIdx.x] = -(smem[0] + smem[1] + smem[2] + smem[3]);
}

// ---------------------------------------------------------------------------
// Kernel 3: final reduce of the partial sums -> out[0].
// ---------------------------------------------------------------------------
__global__ __launch_bounds__(256) void tau_loss_final(
    const float* __restrict__ ws, int m, float inv_div,
    float* __restrict__ out) {
    float a = 0.f;
    for (int i = threadIdx.x; i < m; i += 256)
        a += ws[i];

    #pragma unroll
    for (int off = 32; off > 0; off >>= 1)
        a += __shfl_down(a, off, 64);

    __shared__ float smem[4];
    int wave = threadIdx.x >> 6;
    int lane = threadIdx.x & 63;
    if (lane == 0) smem[wave] = a;
    __syncthreads();
    if (threadIdx.x == 0)
        out[0] = (smem[0] + smem[1] + smem[2] + smem[3]) * inv_div;
}

extern "C" void kernel_launch(void* const* d_in, const int* in_sizes, int n_in,
                              void* d_out, int out_size, void* d_ws, size_t ws_size,
                              hipStream_t stream) {
    const float* tau = (const float*)d_in[0];
    const float* dt  = (const float*)d_in[1];
    const int* offsets = (const int*)d_in[2];
    float* out = (float*)d_out;
    float* ws = (float*)d_ws;

    const int n = in_sizes[0];
    const int n_off = in_sizes[2];          // B + 1
    const int nseg = n_off - 1;
    const float inv_div = 1.0f / (float)n_off;

    tau_loss_main<<<MAIN_BLOCKS, THREADS, 0, stream>>>(
        (const float4*)tau, (const float4*)dt, tau, dt, ws, n);

    int bblocks = (nseg + BND_THREADS - 1) / BND_THREADS;
    if (bblocks < 1) bblocks = 1;
    tau_loss_boundary<<<bblocks, BND_THREADS, 0, stream>>>(tau, dt, offsets, ws, nseg);

    tau_loss_final<<<1, 256, 0, stream>>>(ws, MAIN_BLOCKS + bblocks, inv_div, out);
}

// Round 6
// 32.822 us; speedup vs baseline: 2.9024x; 1.0425x over previous
//
#include <hip/hip_runtime.h>

typedef float f32x4 __attribute__((ext_vector_type(4)));

#define EPS 1e-5f
#define THREADS 256
#define MAIN_BLOCKS 2048
#define SUPER 2048               // f32x4 elements per superchunk (32 KB/array)
#define BND_THREADS 256

// ---- forced async load: compiler cannot serialize or shrink the batch ----
#define GLOAD(dst, addr) \
  asm volatile("global_load_dwordx4 %0, %1, off" : "=v"(dst) : "v"(addr) : "memory")

// counted wait + scheduling fence (rule #18: sched_barrier needed so compute
// is not hoisted above the waitcnt)
#define SWAIT(n) \
  asm volatile("s_waitcnt vmcnt(" #n ")" ::: "memory"); \
  __builtin_amdgcn_sched_barrier(0)

#define NLL4(T, E) \
  a0 += __logf(T.x) + __fdividef(E.x + EPS, T.x); \
  a1 += __logf(T.y) + __fdividef(E.y + EPS, T.y); \
  a2 += __logf(T.z) + __fdividef(E.z + EPS, T.z); \
  a3 += __logf(T.w) + __fdividef(E.w + EPS, T.w)

// issue one 16-load bank, pairwise t/e (oldest-first order = compute order)
#define ISSUE(T, E, P, Q) \
  GLOAD(T##0, P + 0 * THREADS); GLOAD(E##0, Q + 0 * THREADS); \
  GLOAD(T##1, P + 1 * THREADS); GLOAD(E##1, Q + 1 * THREADS); \
  GLOAD(T##2, P + 2 * THREADS); GLOAD(E##2, Q + 2 * THREADS); \
  GLOAD(T##3, P + 3 * THREADS); GLOAD(E##3, Q + 3 * THREADS); \
  GLOAD(T##4, P + 4 * THREADS); GLOAD(E##4, Q + 4 * THREADS); \
  GLOAD(T##5, P + 5 * THREADS); GLOAD(E##5, Q + 5 * THREADS); \
  GLOAD(T##6, P + 6 * THREADS); GLOAD(E##6, Q + 6 * THREADS); \
  GLOAD(T##7, P + 7 * THREADS); GLOAD(E##7, Q + 7 * THREADS)

// consume a bank while 16 loads of the OTHER bank stay in flight
#define COMPUTE16(T, E) \
  SWAIT(28); NLL4(T##0, E##0); NLL4(T##1, E##1); \
  SWAIT(24); NLL4(T##2, E##2); NLL4(T##3, E##3); \
  SWAIT(20); NLL4(T##4, E##4); NLL4(T##5, E##5); \
  SWAIT(16); NLL4(T##6, E##6); NLL4(T##7, E##7)

// consume the last pending bank (nothing else outstanding)
#define COMPUTE0(T, E) \
  SWAIT(12); NLL4(T##0, E##0); NLL4(T##1, E##1); \
  SWAIT(8);  NLL4(T##2, E##2); NLL4(T##3, E##3); \
  SWAIT(4);  NLL4(T##4, E##4); NLL4(T##5, E##5); \
  SWAIT(0);  NLL4(T##6, E##6); NLL4(T##7, E##7)

// ---------------------------------------------------------------------------
// Kernel 1: streaming sum of nll = log(tau) + (dt+eps)/tau over all N.
// Double-banked software pipeline: issue bank s+1, compute bank s under
// counted vmcnt — the per-wave load queue never drains in steady state.
// ---------------------------------------------------------------------------
__global__ __launch_bounds__(THREADS, 2) void tau_loss_main(
    const f32x4* __restrict__ t4,
    const f32x4* __restrict__ d4,
    const float* __restrict__ tau,
    const float* __restrict__ dt,
    float* __restrict__ ws,
    int n) {
    const int n4 = n >> 2;
    const int nsuper = n4 / SUPER;

    float a0 = 0.f, a1 = 0.f, a2 = 0.f, a3 = 0.f;

    f32x4 tA0, tA1, tA2, tA3, tA4, tA5, tA6, tA7;
    f32x4 eA0, eA1, eA2, eA3, eA4, eA5, eA6, eA7;
    f32x4 tB0, tB1, tB2, tB3, tB4, tB5, tB6, tB7;
    f32x4 eB0, eB1, eB2, eB3, eB4, eB5, eB6, eB7;

    int s = (int)blockIdx.x;
    if (s < nsuper) {
        const f32x4* pt = t4 + s * SUPER + (int)threadIdx.x;
        const f32x4* pe = d4 + s * SUPER + (int)threadIdx.x;
        ISSUE(tA, eA, pt, pe);
        s += MAIN_BLOCKS;

        while (s < nsuper) {
            pt = t4 + s * SUPER + (int)threadIdx.x;
            pe = d4 + s * SUPER + (int)threadIdx.x;
            ISSUE(tB, eB, pt, pe);
            COMPUTE16(tA, eA);
            s += MAIN_BLOCKS;
            if (s < nsuper) {
                pt = t4 + s * SUPER + (int)threadIdx.x;
                pe = d4 + s * SUPER + (int)threadIdx.x;
                ISSUE(tA, eA, pt, pe);
                COMPUTE16(tB, eB);
                s += MAIN_BLOCKS;
            } else {
                COMPUTE0(tB, eB);
                goto main_done;
            }
        }
        COMPUTE0(tA, eA);
        main_done: ;
    }

    // scalar tail: elements past nsuper*SUPER*4 (none at N=16.7M; kept general)
    if (blockIdx.x == 0) {
        for (int i = nsuper * (SUPER * 4) + (int)threadIdx.x; i < n; i += THREADS) {
            float t = tau[i];
            a0 += __logf(t) + __fdividef(dt[i] + EPS, t);
        }
    }

    float acc = (a0 + a1) + (a2 + a3);

    #pragma unroll
    for (int off = 32; off > 0; off >>= 1)
        acc += __shfl_down(acc, off, 64);

    __shared__ float smem[THREADS / 64];
    int wave = threadIdx.x >> 6;
    int lane = threadIdx.x & 63;
    if (lane == 0) smem[wave] = acc;
    __syncthreads();
    if (threadIdx.x == 0)
        ws[blockIdx.x] = smem[0] + smem[1] + smem[2] + smem[3];
}

// ---------------------------------------------------------------------------
// Kernel 2: boundary (first & last of each segment) contributions, negated.
// ---------------------------------------------------------------------------
__global__ __launch_bounds__(BND_THREADS) void tau_loss_boundary(
    const float* __restrict__ tau,
    const float* __restrict__ dt,
    const int* __restrict__ offsets,
    float* __restrict__ ws,
    int nseg) {
    int k = blockIdx.x * blockDim.x + threadIdx.x;

    float sub = 0.0f;
    if (k < nseg) {
        int s = offsets[k];
        int e = offsets[k + 1] - 1;
        float ts = tau[s];
        sub = __logf(ts) + __fdividef(dt[s] + EPS, ts);
        if (e != s) {
            float te = tau[e];
            sub += __logf(te) + __fdividef(dt[e] + EPS, te);
        }
    }

    #pragma unroll
    for (int off = 32; off > 0; off >>= 1)
        sub += __shfl_down(sub, off, 64);

    __shared__ float smem[BND_THREADS / 64];
    int wave = threadIdx.x >> 6;
    int lane = threadIdx.x & 63;
    if (lane == 0) smem[wave] = sub;
    __syncthreads();
    if (threadIdx.x == 0)
        ws[MAIN_BLOCKS + blockIdx.x] = -(smem[0] + smem[1] + smem[2] + smem[3]);
}

// ---------------------------------------------------------------------------
// Kernel 3: final reduce of the partial sums -> out[0].
// ---------------------------------------------------------------------------
__global__ __launch_bounds__(256) void tau_loss_final(
    const float* __restrict__ ws, int m, float inv_div,
    float* __restrict__ out) {
    float a = 0.f;
    for (int i = threadIdx.x; i < m; i += 256)
        a += ws[i];

    #pragma unroll
    for (int off = 32; off > 0; off >>= 1)
        a += __shfl_down(a, off, 64);

    __shared__ float smem[4];
    int wave = threadIdx.x >> 6;
    int lane = threadIdx.x & 63;
    if (lane == 0) smem[wave] = a;
    __syncthreads();
    if (threadIdx.x == 0)
        out[0] = (smem[0] + smem[1] + smem[2] + smem[3]) * inv_div;
}

extern "C" void kernel_launch(void* const* d_in, const int* in_sizes, int n_in,
                              void* d_out, int out_size, void* d_ws, size_t ws_size,
                              hipStream_t stream) {
    const float* tau = (const float*)d_in[0];
    const float* dt  = (const float*)d_in[1];
    const int* offsets = (const int*)d_in[2];
    float* out = (float*)d_out;
    float* ws = (float*)d_ws;

    const int n = in_sizes[0];
    const int n_off = in_sizes[2];          // B + 1
    const int nseg = n_off - 1;
    const float inv_div = 1.0f / (float)n_off;

    tau_loss_main<<<MAIN_BLOCKS, THREADS, 0, stream>>>(
        (const f32x4*)tau, (const f32x4*)dt, tau, dt, ws, n);

    int bblocks = (nseg + BND_THREADS - 1) / BND_THREADS;
    if (bblocks < 1) bblocks = 1;
    tau_loss_boundary<<<bblocks, BND_THREADS, 0, stream>>>(tau, dt, offsets, ws, nseg);

    tau_loss_final<<<1, 256, 0, stream>>>(ws, MAIN_BLOCKS + bblocks, inv_div, out);
}